// Round 1
// baseline (268.964 us; speedup 1.0000x reference)
//
#include <hip/hip_runtime.h>
#include <cstdint>
#include <cstddef>

typedef unsigned short u16;
typedef __attribute__((ext_vector_type(8))) short bf16x8;
typedef __attribute__((ext_vector_type(4))) float f32x4;

#define DEV __device__ __forceinline__

DEV u16 f2bf(float f) {
  uint32_t u = __float_as_uint(f);
  u += 0x7fffu + ((u >> 16) & 1u);
  return (u16)(u >> 16);
}

DEV f32x4 mfma16(bf16x8 a, bf16x8 b, f32x4 c) {
  return __builtin_amdgcn_mfma_f32_16x16x32_bf16(a, b, c, 0, 0, 0);
}

static constexpr int BATCH = 4;
static constexpr int C = 256;    // in/out channels
static constexpr int CI = 128;   // inter channels
static constexpr int N = 4096;   // tokens (64x64)

// ---------------- weight convert (all four weight mats are 32768 elems) ----
__global__ __launch_bounds__(256) void cvt_w(const float* __restrict__ a,
                                             const float* __restrict__ b,
                                             const float* __restrict__ c,
                                             const float* __restrict__ d,
                                             u16* __restrict__ oa, u16* __restrict__ ob,
                                             u16* __restrict__ oc, u16* __restrict__ od) {
  int i = blockIdx.x * 256 + threadIdx.x;
  oa[i] = f2bf(a[i]);
  ob[i] = f2bf(b[i]);
  oc[i] = f2bf(c[i]);
  od[i] = f2bf(d[i]);
}

// ---------------- QKV projection -------------------------------------------
// Q[b][n][ci] = sum_c qw[ci][c]*x[b][c][n] + qb[ci]      (bf16 out)
// K[b][n][ci] = sum_c kw[ci][c]*rgbd[b][c][n] + kb[ci]   (bf16 out, token-major)
// Vt[b][ci][n] = sum_c vw[ci][c]*rgbd[b][c][n] + vb[ci]  (bf16 out, ci-major)
__global__ __launch_bounds__(256) void proj_kernel(
    const float* __restrict__ x, const float* __restrict__ rgbd,
    const u16* __restrict__ Wq, const u16* __restrict__ Wk, const u16* __restrict__ Wv,
    const float* __restrict__ qb, const float* __restrict__ kb, const float* __restrict__ vb,
    u16* __restrict__ Qb, u16* __restrict__ Kb, u16* __restrict__ Vtb) {
  __shared__ __align__(16) u16 xT[64][C + 8];  // +8 pad: A-frag reads ~conflict-free
  __shared__ __align__(16) u16 rT[64][C + 8];
  const int b = blockIdx.y;
  const int n0 = blockIdx.x * 64;
  const int t = threadIdx.x;
  {
    const int tok = t & 63, cs = t >> 6;
    const float* xb = x + (size_t)b * C * N + n0;
    const float* rb = rgbd + (size_t)b * C * N + n0;
    for (int c0 = 0; c0 < C; c0 += 4) {
      int c = c0 + cs;
      xT[tok][c] = f2bf(xb[(size_t)c * N + tok]);
      rT[tok][c] = f2bf(rb[(size_t)c * N + tok]);
    }
  }
  __syncthreads();
  const int w = t >> 6, lane = t & 63, g = lane >> 4, cl = lane & 15;

  // ---- Q (from xT) and K (from rT): wave w owns tokens w*16..w*16+15 ----
#define PROJ_QK(Sarr, W, bias, Out)                                                   \
  {                                                                                   \
    bf16x8 afr[8];                                                                    \
    _Pragma("unroll") for (int ks = 0; ks < 8; ++ks)                                  \
        afr[ks] = *(const bf16x8*)&Sarr[w * 16 + cl][ks * 32 + g * 8];                \
    _Pragma("unroll") for (int ct = 0; ct < 8; ++ct) {                                \
      f32x4 acc = {0.f, 0.f, 0.f, 0.f};                                               \
      _Pragma("unroll") for (int ks = 0; ks < 8; ++ks) {                              \
        bf16x8 bb = *(const bf16x8*)&W[(size_t)(ct * 16 + cl) * C + ks * 32 + g * 8]; \
        acc = mfma16(afr[ks], bb, acc);                                               \
      }                                                                               \
      float bv = bias[ct * 16 + cl];                                                  \
      _Pragma("unroll") for (int r = 0; r < 4; ++r) {                                 \
        int tok = n0 + w * 16 + g * 4 + r;                                            \
        Out[((size_t)b * N + tok) * CI + ct * 16 + cl] = f2bf(acc[r] + bv);           \
      }                                                                               \
    }                                                                                 \
  }

  PROJ_QK(xT, Wq, qb, Qb)
  PROJ_QK(rT, Wk, kb, Kb)
#undef PROJ_QK

  // ---- Vt: wave w owns ci rows w*32..w*32+31, cols = 64 tokens ----
  #pragma unroll
  for (int rt = 0; rt < 2; ++rt) {
    bf16x8 aw[8];
    #pragma unroll
    for (int ks = 0; ks < 8; ++ks)
      aw[ks] = *(const bf16x8*)&Wv[(size_t)(w * 32 + rt * 16 + cl) * C + ks * 32 + g * 8];
    #pragma unroll
    for (int ct = 0; ct < 4; ++ct) {
      f32x4 acc = {0.f, 0.f, 0.f, 0.f};
      #pragma unroll
      for (int ks = 0; ks < 8; ++ks) {
        bf16x8 bb = *(const bf16x8*)&rT[ct * 16 + cl][ks * 32 + g * 8];
        acc = mfma16(aw[ks], bb, acc);
      }
      #pragma unroll
      for (int r = 0; r < 4; ++r) {
        int o = w * 32 + rt * 16 + g * 4 + r;
        Vtb[((size_t)b * CI + o) * N + n0 + ct * 16 + cl] = f2bf(acc[r] + vb[o]);
      }
    }
  }
}

// ---------------- flash attention ------------------------------------------
// Per block: one batch, 64 queries (4 waves x 16). Iterate keys in tiles of 64.
// Swapped QK^T: S^T[key][q] = mfma(A=K rows, B=Q rows) -> softmax state is
// per-lane scalar (q = lane&15). P re-fragmented through small per-wave LDS.
// K/V tiles staged in LDS with XOR slot swizzle (conflict-balanced reads).
__global__ __launch_bounds__(256) void attn_kernel(
    const u16* __restrict__ Qb, const u16* __restrict__ Kb,
    const u16* __restrict__ Vtb, u16* __restrict__ Ob) {
  __shared__ __align__(16) u16 Klds[64][128];   // [key][ci], slot s holds ci-chunk s^(key&15)
  __shared__ __align__(16) u16 Vlds[128][64];   // [ci][key], slot s holds key-chunk s^(ci&7)
  __shared__ __align__(16) u16 Plds[4][16][80]; // per-wave [q][key], +16 pad
  const int b = blockIdx.y;
  const int q0 = blockIdx.x * 64;
  const int t = threadIdx.x;
  const int w = t >> 6, lane = t & 63, g = lane >> 4, cl = lane & 15;

  const u16* Qg = Qb + ((size_t)b * N + q0 + w * 16) * CI;
  bf16x8 qf[4];  // hoisted Q B-fragments (q = cl, ci chunks)
  #pragma unroll
  for (int ks = 0; ks < 4; ++ks)
    qf[ks] = *(const bf16x8*)(Qg + (size_t)cl * CI + ks * 32 + g * 8);

  f32x4 oacc[8];
  #pragma unroll
  for (int i = 0; i < 8; ++i) oacc[i] = {0.f, 0.f, 0.f, 0.f};
  float m = -1e30f, l = 0.f;

  const u16* Kg = Kb + (size_t)b * N * CI;
  const u16* Vg = Vtb + (size_t)b * CI * N;

  for (int k0 = 0; k0 < N; k0 += 64) {
    // cooperative stage: K tile 16KB + V tile 16KB, pre-swizzled on source side
    #pragma unroll
    for (int i = 0; i < 4; ++i) {
      int idx = t + i * 256;
      int r = idx >> 4, s = idx & 15;
      int ss = s ^ (r & 15);
      *(f32x4*)&Klds[r][s * 8] = *(const f32x4*)(Kg + (size_t)(k0 + r) * CI + ss * 8);
    }
    #pragma unroll
    for (int i = 0; i < 4; ++i) {
      int idx = t + i * 256;
      int r = idx >> 3, s = idx & 7;
      int ss = s ^ (r & 7);
      *(f32x4*)&Vlds[r][s * 8] = *(const f32x4*)(Vg + (size_t)r * N + k0 + ss * 8);
    }
    __syncthreads();

    // S^T tiles: rows = keys (ct*16+cl), cols = 16 queries
    f32x4 st[4];
    #pragma unroll
    for (int ct = 0; ct < 4; ++ct) {
      f32x4 acc = {0.f, 0.f, 0.f, 0.f};
      #pragma unroll
      for (int ks = 0; ks < 4; ++ks) {
        int slot = (ks * 4 + g) ^ cl;  // (ct*16+cl)&15 == cl
        bf16x8 kf = *(const bf16x8*)&Klds[ct * 16 + cl][slot * 8];
        acc = mfma16(kf, qf[ks], acc);
      }
      st[ct] = acc;
    }

    // online softmax; lane owns q = cl, holds keys ct*16 + g*4 + r
    float tmax = -1e30f;
    #pragma unroll
    for (int ct = 0; ct < 4; ++ct)
      #pragma unroll
      for (int r = 0; r < 4; ++r) tmax = fmaxf(tmax, st[ct][r]);
    tmax = fmaxf(tmax, __shfl_xor(tmax, 16));
    tmax = fmaxf(tmax, __shfl_xor(tmax, 32));
    const float mn = fmaxf(m, tmax);
    const float alpha = __expf(m - mn);
    m = mn;
    float ls = 0.f;
    uint32_t pk[8];
    #pragma unroll
    for (int ct = 0; ct < 4; ++ct) {
      float p0 = __expf(st[ct][0] - mn);
      float p1 = __expf(st[ct][1] - mn);
      float p2 = __expf(st[ct][2] - mn);
      float p3 = __expf(st[ct][3] - mn);
      ls += (p0 + p1) + (p2 + p3);
      pk[ct * 2 + 0] = (uint32_t)f2bf(p0) | ((uint32_t)f2bf(p1) << 16);
      pk[ct * 2 + 1] = (uint32_t)f2bf(p2) | ((uint32_t)f2bf(p3) << 16);
    }
    ls += __shfl_xor(ls, 16);
    ls += __shfl_xor(ls, 32);
    l = l * alpha + ls;

    // P -> per-wave LDS in [q][key] layout (paired-key dword writes)
    #pragma unroll
    for (int ct = 0; ct < 4; ++ct) {
      *(uint32_t*)&Plds[w][cl][ct * 16 + g * 4] = pk[ct * 2];
      *(uint32_t*)&Plds[w][cl][ct * 16 + g * 4 + 2] = pk[ct * 2 + 1];
    }

    // rescale accumulator: alpha lives at lane (q), O rows are q = g*4+r
    #pragma unroll
    for (int r = 0; r < 4; ++r) {
      float ar = __shfl(alpha, g * 4 + r);
      #pragma unroll
      for (int ct2 = 0; ct2 < 8; ++ct2) oacc[ct2][r] *= ar;
    }

    // PV: A = P rows (q=cl), B = V from swizzled Vlds
    bf16x8 pa0 = *(const bf16x8*)&Plds[w][cl][g * 8];
    bf16x8 pa1 = *(const bf16x8*)&Plds[w][cl][32 + g * 8];
    const int s0 = (0 * 4 + g) ^ (cl & 7);
    const int s1 = (1 * 4 + g) ^ (cl & 7);
    #pragma unroll
    for (int ct2 = 0; ct2 < 8; ++ct2) {
      bf16x8 v0 = *(const bf16x8*)&Vlds[ct2 * 16 + cl][s0 * 8];
      bf16x8 v1 = *(const bf16x8*)&Vlds[ct2 * 16 + cl][s1 * 8];
      oacc[ct2] = mfma16(pa0, v0, oacc[ct2]);
      oacc[ct2] = mfma16(pa1, v1, oacc[ct2]);
    }
    __syncthreads();
  }

  // epilogue: normalize by l (per q), store O[b][q][ci] bf16
  #pragma unroll
  for (int r = 0; r < 4; ++r) {
    float lr = __shfl(l, g * 4 + r);
    float inv = 1.0f / lr;
    const int q = q0 + w * 16 + g * 4 + r;
    #pragma unroll
    for (int ct2 = 0; ct2 < 8; ++ct2)
      Ob[((size_t)b * N + q) * CI + ct2 * 16 + cl] = f2bf(oacc[ct2][r] * inv);
  }
}

// ---------------- output projection + residual -----------------------------
// out[b][o][n] = rgbd[b][o][n] + ob[o] + sum_ci ow[o][ci]*O[b][n][ci]
__global__ __launch_bounds__(256) void outproj_kernel(
    const u16* __restrict__ Ob, const u16* __restrict__ Wo,
    const float* __restrict__ obias, const float* __restrict__ rgbd,
    float* __restrict__ out) {
  const int b = blockIdx.y;
  const int n0 = blockIdx.x * 64;
  const int t = threadIdx.x;
  const int w = t >> 6, lane = t & 63, g = lane >> 4, cl = lane & 15;

  f32x4 acc[4][4];  // [rt][ct]
  #pragma unroll
  for (int i = 0; i < 4; ++i)
    #pragma unroll
    for (int j = 0; j < 4; ++j) acc[i][j] = {0.f, 0.f, 0.f, 0.f};

  #pragma unroll
  for (int ks = 0; ks < 4; ++ks) {
    bf16x8 bo[4];
    #pragma unroll
    for (int ct = 0; ct < 4; ++ct)
      bo[ct] = *(const bf16x8*)&Ob[((size_t)b * N + n0 + ct * 16 + cl) * CI + ks * 32 + g * 8];
    #pragma unroll
    for (int rt = 0; rt < 4; ++rt) {
      bf16x8 aw = *(const bf16x8*)&Wo[(size_t)(w * 64 + rt * 16 + cl) * CI + ks * 32 + g * 8];
      #pragma unroll
      for (int ct = 0; ct < 4; ++ct) acc[rt][ct] = mfma16(aw, bo[ct], acc[rt][ct]);
    }
  }
  #pragma unroll
  for (int rt = 0; rt < 4; ++rt) {
    #pragma unroll
    for (int r = 0; r < 4; ++r) {
      const int o = w * 64 + rt * 16 + g * 4 + r;
      const float bb = obias[o];
      #pragma unroll
      for (int ct = 0; ct < 4; ++ct) {
        size_t idx = ((size_t)b * C + o) * N + n0 + ct * 16 + cl;
        out[idx] = rgbd[idx] + bb + acc[rt][ct][r];
      }
    }
  }
}

// ---------------- launch ----------------------------------------------------
extern "C" void kernel_launch(void* const* d_in, const int* in_sizes, int n_in,
                              void* d_out, int out_size, void* d_ws, size_t ws_size,
                              hipStream_t stream) {
  (void)in_sizes; (void)n_in; (void)out_size; (void)ws_size;
  const float* rgbd = (const float*)d_in[0];
  const float* x    = (const float*)d_in[1];
  const float* q_w  = (const float*)d_in[2];
  const float* q_b  = (const float*)d_in[3];
  const float* k_w  = (const float*)d_in[4];
  const float* k_b  = (const float*)d_in[5];
  const float* v_w  = (const float*)d_in[6];
  const float* v_b  = (const float*)d_in[7];
  const float* o_w  = (const float*)d_in[8];
  const float* o_b  = (const float*)d_in[9];
  float* out = (float*)d_out;

  char* ws = (char*)d_ws;
  const size_t szQKV = (size_t)BATCH * N * CI * sizeof(u16);  // 4 MB each
  u16* Qb  = (u16*)(ws);
  u16* Kb  = (u16*)(ws + szQKV);
  u16* Vtb = (u16*)(ws + 2 * szQKV);
  u16* Ob  = (u16*)(ws + 3 * szQKV);
  u16* Wq  = (u16*)(ws + 4 * szQKV);
  u16* Wk  = Wq + (size_t)CI * C;
  u16* Wv  = Wk + (size_t)CI * C;
  u16* Wo  = Wv + (size_t)CI * C;

  cvt_w<<<dim3((C * CI) / 256), 256, 0, stream>>>(q_w, k_w, v_w, o_w, Wq, Wk, Wv, Wo);
  proj_kernel<<<dim3(N / 64, BATCH), 256, 0, stream>>>(x, rgbd, Wq, Wk, Wv,
                                                       q_b, k_b, v_b, Qb, Kb, Vtb);
  attn_kernel<<<dim3(N / 64, BATCH), 256, 0, stream>>>(Qb, Kb, Vtb, Ob);
  outproj_kernel<<<dim3(N / 64, BATCH), 256, 0, stream>>>(Ob, Wo, o_b, rgbd, out);
}